// Round 12
// baseline (234.642 us; speedup 1.0000x reference)
//
#include <hip/hip_runtime.h>

#define NT 8
#define ND 16
#define NH 16
#define NW 16
#define NC 32
#define NB 65536
#define NCELLS (5 * 13 * 13)   // 845 span-base cells (t,d,h)
#define CAP 1024               // per-cell perm slab (expected max ~333, 38 sigma)
#define CHUNKQ 64              // queries per main block
#define NCHUNKS_PER_CELL (CAP / CHUNKQ)   // 16

typedef __attribute__((ext_vector_type(8))) _Float16 half8;
typedef __attribute__((ext_vector_type(4))) _Float16 half4;
typedef __attribute__((ext_vector_type(2))) _Float16 half2v;

union H8 {
    half8 v;
    half2v h2[4];
};

// ---- shared span-base logic (IDENTICAL in binning + main) ----
template <int N>
__device__ __forceinline__ int span_base(float u) {
    float s = u * (float)(N - 1);
    float fi = fminf(fmaxf(floorf(s), 0.0f), (float)(N - 2));
    int i = (int)fi;
    return (i == 0) ? 0 : ((i == N - 2) ? (N - 4) : (i - 1));
}

// Span-based per-dim setup: span b..b+3 (in-bounds) + 4 weights with the
// linear-extrapolation padding folded in. Validated rounds 3-11 (absmax 7.8e-3).
template <int N>
__device__ __forceinline__ void dim_setup_span(float u, int& b, float w[4]) {
    float s = u * (float)(N - 1);
    float fi = fminf(fmaxf(floorf(s), 0.0f), (float)(N - 2));
    float t = s - fi;
    int i = (int)fi;
    float t2 = t * t, t3 = t2 * t;
    const float c6 = 1.0f / 6.0f;
    float w0 = (1.0f - 3.0f * t + 3.0f * t2 - t3) * c6;
    float w1 = (4.0f - 6.0f * t2 + 3.0f * t3) * c6;
    float w2 = (1.0f + 3.0f * t + 3.0f * t2 - 3.0f * t3) * c6;
    float w3 = t3 * c6;
    if (i == 0) {
        b = 0;
        w[0] = w1 + 2.0f * w0; w[1] = w2 - w0; w[2] = w3; w[3] = 0.0f;
    } else if (i == N - 2) {
        b = N - 4;
        w[0] = 0.0f; w[1] = w0; w[2] = w1 - w3; w[3] = w2 + 2.0f * w3;
    } else {
        b = i - 1;
        w[0] = w0; w[1] = w1; w[2] = w2; w[3] = w3;
    }
}

// ---- fused prep: f32->fp16 convert (blocks 0..1023) + count/perm (1024..1279)
// perm is a fixed-capacity slab per cell: no scan, no scatter kernel.
// Output is rank-order independent, so atomicAdd nondeterminism is benign.
__global__ __launch_bounds__(256) void prep_kernel(
    const float4* __restrict__ g, half4* __restrict__ hg,
    const float4* __restrict__ u4, int* __restrict__ count,
    int* __restrict__ perm) {
    int b = blockIdx.x;
    int t = threadIdx.x;
    if (b < 1024) {
        int i = b * 256 + t;
        float4 v = g[i];
        half4 h;
        h[0] = (_Float16)v.x;
        h[1] = (_Float16)v.y;
        h[2] = (_Float16)v.z;
        h[3] = (_Float16)v.w;
        hg[i] = h;
    } else {
        int q = (b - 1024) * 256 + t;
        float4 uu = u4[q];
        int bt = span_base<NT>(uu.x);
        int bd = span_base<ND>(uu.y);
        int bh = span_base<NH>(uu.z);
        int cell = (bt * 13 + bd) * 13 + bh;
        int rank = atomicAdd(&count[cell], 1);
        if (rank < CAP) perm[cell * CAP + rank] = q;
    }
}

// ---- main: grid = NCELLS*16; block = one <=64-query chunk of a cell.
// 1024 threads (64 slots x 16 lanes), 64KB LDS -> 2 blocks/CU possible.
// Plain reg->LDS staging (round-10 proven; global_load_lds waterfalled in r11).
__global__ __launch_bounds__(1024) void spline4d_cell_kernel(
    const float* __restrict__ u, const uint4* __restrict__ hgrid,
    const int* __restrict__ count, const int* __restrict__ perm,
    float4* __restrict__ out) {
    int cell = blockIdx.x >> 4;
    int kch = blockIdx.x & (NCHUNKS_PER_CELL - 1);
    int n = min(count[cell], CAP);
    int start = kch * CHUNKQ;
    if (start >= n) return;      // empty chunk: exit before staging
    int len = min(CHUNKQ, n - start);

    __shared__ uint4 smem[4096];   // 64 KB: 64 rows x 1KB

    int bt = cell / 169;
    int r0 = cell - bt * 169;
    int bd = r0 / 13;
    int bh = r0 - bd * 13;

    // stage 64 rows (i,j,k), each 1KB (16 w-points x 64B): 4 iters/thread
    {
        int idx = (int)threadIdx.x;
#pragma unroll
        for (int it = 0; it < 4; ++it) {
            int lrow = idx >> 6;
            int chunk = idx & 63;
            int i = lrow >> 4, j = (lrow >> 2) & 3, k = lrow & 3;
            int R = ((bt + i) * ND + (bd + j)) * NH + (bh + k);
            smem[idx] = hgrid[R * 64 + chunk];
            idx += 1024;
        }
    }
    __syncthreads();

    int slot = (int)threadIdx.x >> 4;
    int s = (int)threadIdx.x & 15;
    if (slot >= len) return;

    const half8* slds = reinterpret_cast<const half8*>(smem);
    int q = perm[cell * CAP + start + slot];

    float4 uu = reinterpret_cast<const float4*>(u)[q];

    int xbt, xbd, xbh, bw;
    float wtv[4], wdv[4], whv[4], wwv[4];
    dim_setup_span<NT>(uu.x, xbt, wtv);
    dim_setup_span<ND>(uu.y, xbd, wdv);
    dim_setup_span<NH>(uu.z, xbh, whv);
    dim_setup_span<NW>(uu.w, bw, wwv);
    // xbt==bt etc. by construction

    int wp = s >> 2;
    float wlane = (wp & 2) ? ((wp & 1) ? wwv[3] : wwv[2])
                           : ((wp & 1) ? wwv[1] : wwv[0]);

    half2v whW2[4];
#pragma unroll
    for (int k = 0; k < 4; ++k) {
        _Float16 h = (_Float16)(whv[k] * wlane);
        whW2[k][0] = h;
        whW2[k][1] = h;
    }

    float facc[8];
#pragma unroll
    for (int c = 0; c < 8; ++c) facc[c] = 0.0f;
    half2v a01 = {0, 0}, a23 = {0, 0}, a45 = {0, 0}, a67 = {0, 0};

    int lbase = (bw << 2) + s;

#pragma unroll
    for (int i = 0; i < 4; ++i) {
#pragma unroll
        for (int j = 0; j < 4; ++j) {
            _Float16 wtdh = (_Float16)(wtv[i] * wdv[j]);
            half2v wtd2 = {wtdh, wtdh};
#pragma unroll
            for (int k = 0; k < 4; ++k) {
                int lidx = ((i << 4) + (j << 2) + k) * 64 + lbase;
                H8 P;
                P.v = slds[lidx];
                half2v uw = wtd2 * whW2[k];
                a01 += P.h2[0] * uw;
                a23 += P.h2[1] * uw;
                a45 += P.h2[2] * uw;
                a67 += P.h2[3] * uw;
            }
        }
        if (i == 1 || i == 3) {
            facc[0] += (float)a01[0]; facc[1] += (float)a01[1];
            facc[2] += (float)a23[0]; facc[3] += (float)a23[1];
            facc[4] += (float)a45[0]; facc[5] += (float)a45[1];
            facc[6] += (float)a67[0]; facc[7] += (float)a67[1];
            a01 = (half2v){0, 0}; a23 = (half2v){0, 0};
            a45 = (half2v){0, 0}; a67 = (half2v){0, 0};
        }
    }

#pragma unroll
    for (int c = 0; c < 8; ++c) {
        facc[c] += __shfl_xor(facc[c], 4);
        facc[c] += __shfl_xor(facc[c], 8);
    }

    if (s < 4) {
        out[q * 8 + s * 2] = make_float4(facc[0], facc[1], facc[2], facc[3]);
        out[q * 8 + s * 2 + 1] = make_float4(facc[4], facc[5], facc[6], facc[7]);
    }
}

// ---- fallback (ws too small for perm slab): round-6 direct fp16, 52.5us ----
__global__ __launch_bounds__(256) void convert_fp16_kernel(
    const float4* __restrict__ g, half4* __restrict__ hg) {
    int i = blockIdx.x * blockDim.x + threadIdx.x;
    float4 v = g[i];
    half4 h;
    h[0] = (_Float16)v.x;
    h[1] = (_Float16)v.y;
    h[2] = (_Float16)v.z;
    h[3] = (_Float16)v.w;
    hg[i] = h;
}

__global__ __launch_bounds__(256) void spline4d_fp16_kernel(
    const float* __restrict__ u, const half8* __restrict__ grid,
    float4* __restrict__ out) {
    int tid = blockIdx.x * blockDim.x + threadIdx.x;
    int q = tid >> 4;
    int s = tid & 15;

    float4 uu = reinterpret_cast<const float4*>(u)[q];

    int bt, bd, bh, bw;
    float wtv[4], wdv[4], whv[4], wwv[4];
    dim_setup_span<NT>(uu.x, bt, wtv);
    dim_setup_span<ND>(uu.y, bd, wdv);
    dim_setup_span<NH>(uu.z, bh, whv);
    dim_setup_span<NW>(uu.w, bw, wwv);

    int wp = s >> 2;
    float wlane = (wp & 2) ? ((wp & 1) ? wwv[3] : wwv[2])
                           : ((wp & 1) ? wwv[1] : wwv[0]);

    half2v whW2[4];
#pragma unroll
    for (int k = 0; k < 4; ++k) {
        _Float16 h = (_Float16)(whv[k] * wlane);
        whW2[k][0] = h;
        whW2[k][1] = h;
    }

    int base = ((((bt * ND + bd) * NH + bh) * NW + bw) << 2) + s;

    float facc[8];
#pragma unroll
    for (int c = 0; c < 8; ++c) facc[c] = 0.0f;
    half2v a01 = {0, 0}, a23 = {0, 0}, a45 = {0, 0}, a67 = {0, 0};

#pragma unroll
    for (int i = 0; i < 4; ++i) {
#pragma unroll
        for (int j = 0; j < 4; ++j) {
            _Float16 wtdh = (_Float16)(wtv[i] * wdv[j]);
            half2v wtd2 = {wtdh, wtdh};
#pragma unroll
            for (int k = 0; k < 4; ++k) {
                int a = base + i * (4 * ND * NH * NW) + j * (4 * NH * NW) +
                        k * (4 * NW);
                H8 P;
                P.v = grid[a];
                half2v uw = wtd2 * whW2[k];
                a01 += P.h2[0] * uw;
                a23 += P.h2[1] * uw;
                a45 += P.h2[2] * uw;
                a67 += P.h2[3] * uw;
            }
        }
        if (i == 1 || i == 3) {
            facc[0] += (float)a01[0]; facc[1] += (float)a01[1];
            facc[2] += (float)a23[0]; facc[3] += (float)a23[1];
            facc[4] += (float)a45[0]; facc[5] += (float)a45[1];
            facc[6] += (float)a67[0]; facc[7] += (float)a67[1];
            a01 = (half2v){0, 0}; a23 = (half2v){0, 0};
            a45 = (half2v){0, 0}; a67 = (half2v){0, 0};
        }
    }

#pragma unroll
    for (int c = 0; c < 8; ++c) {
        facc[c] += __shfl_xor(facc[c], 4);
        facc[c] += __shfl_xor(facc[c], 8);
    }

    if (s < 4) {
        out[q * 8 + s * 2] = make_float4(facc[0], facc[1], facc[2], facc[3]);
        out[q * 8 + s * 2 + 1] = make_float4(facc[4], facc[5], facc[6], facc[7]);
    }
}

extern "C" void kernel_launch(void* const* d_in, const int* in_sizes, int n_in,
                              void* d_out, int out_size, void* d_ws, size_t ws_size,
                              hipStream_t stream) {
    const float* u = (const float*)d_in[0];
    const float* grid_f32 = (const float*)d_in[1];
    float4* out = (float4*)d_out;

    const size_t n_grid_floats = (size_t)NT * ND * NH * NW * NC;  // 1,048,576
    const size_t HG_BYTES = n_grid_floats * 2;                    // 2 MiB

    // workspace layout
    char* ws = (char*)d_ws;
    const size_t OFF_COUNT = HG_BYTES;                       // 8 KB reserve
    const size_t OFF_PERM = OFF_COUNT + 8192;                // 845*1024*4
    const size_t NEED = OFF_PERM + (size_t)NCELLS * CAP * 4; // ~5.47 MB

    if (ws_size >= NEED) {
        half4* hgrid = (half4*)ws;
        int* count = (int*)(ws + OFF_COUNT);
        int* perm = (int*)(ws + OFF_PERM);

        hipMemsetAsync(count, 0, 8192, stream);
        prep_kernel<<<1024 + NB / 256, 256, 0, stream>>>(
            (const float4*)grid_f32, hgrid, (const float4*)u, count, perm);
        spline4d_cell_kernel<<<NCELLS * NCHUNKS_PER_CELL, 1024, 0, stream>>>(
            u, (const uint4*)hgrid, count, perm, out);
    } else if (ws_size >= HG_BYTES) {
        half4* hgrid = (half4*)ws;
        int cvt_blocks = (int)(n_grid_floats / 4 / 256);  // 1024
        convert_fp16_kernel<<<cvt_blocks, 256, 0, stream>>>(
            (const float4*)grid_f32, hgrid);
        int nblocks = NB * 16 / 256;
        spline4d_fp16_kernel<<<nblocks, 256, 0, stream>>>(
            u, (const half8*)hgrid, out);
    }
}

// Round 13
// 67.572 us; speedup vs baseline: 3.4725x; 3.4725x over previous
//
#include <hip/hip_runtime.h>

#define NT 8
#define ND 16
#define NH 16
#define NW 16
#define NC 32
#define NB 65536
#define NCELLS (5 * 13 * 13)   // 845 span-base cells (t,d,h)
#define CAP 768                // per-cell perm slab (expected max ~405; 768=12*64)
#define CHUNKQ 64              // queries per main block (two 32-query passes)
#define MAXCHUNKS (NCELLS + NB / CHUNKQ)   // 845 + 1024 = 1869
#define ROWU4 65               // uint4 per LDS row: 64 data + 1 pad (1040 B)

typedef __attribute__((ext_vector_type(8))) _Float16 half8;
typedef __attribute__((ext_vector_type(4))) _Float16 half4;
typedef __attribute__((ext_vector_type(2))) _Float16 half2v;

union H8 {
    half8 v;
    half2v h2[4];
};

// ---- shared span-base logic (IDENTICAL in binning + main) ----
template <int N>
__device__ __forceinline__ int span_base(float u) {
    float s = u * (float)(N - 1);
    float fi = fminf(fmaxf(floorf(s), 0.0f), (float)(N - 2));
    int i = (int)fi;
    return (i == 0) ? 0 : ((i == N - 2) ? (N - 4) : (i - 1));
}

// Span-based per-dim setup: span b..b+3 (in-bounds) + 4 weights with the
// linear-extrapolation padding folded in. Validated rounds 3-12 (absmax 7.8e-3).
template <int N>
__device__ __forceinline__ void dim_setup_span(float u, int& b, float w[4]) {
    float s = u * (float)(N - 1);
    float fi = fminf(fmaxf(floorf(s), 0.0f), (float)(N - 2));
    float t = s - fi;
    int i = (int)fi;
    float t2 = t * t, t3 = t2 * t;
    const float c6 = 1.0f / 6.0f;
    float w0 = (1.0f - 3.0f * t + 3.0f * t2 - t3) * c6;
    float w1 = (4.0f - 6.0f * t2 + 3.0f * t3) * c6;
    float w2 = (1.0f + 3.0f * t + 3.0f * t2 - 3.0f * t3) * c6;
    float w3 = t3 * c6;
    if (i == 0) {
        b = 0;
        w[0] = w1 + 2.0f * w0; w[1] = w2 - w0; w[2] = w3; w[3] = 0.0f;
    } else if (i == N - 2) {
        b = N - 4;
        w[0] = 0.0f; w[1] = w0; w[2] = w1 - w3; w[3] = w2 + 2.0f * w3;
    } else {
        b = i - 1;
        w[0] = w0; w[1] = w1; w[2] = w2; w[3] = w3;
    }
}

// ---- fused prep: convert (blocks 0..1023) + bin/perm/chunk-append (1024..1279)
// Chunk records appended when rank crosses a CHUNKQ boundary: no scan, no
// scatter. Output is rank-order independent -> atomic nondeterminism benign.
__global__ __launch_bounds__(256) void prep_kernel(
    const float4* __restrict__ g, half4* __restrict__ hg,
    const float4* __restrict__ u4, int* __restrict__ count,
    int* __restrict__ perm, uint2* __restrict__ chunks,
    int* __restrict__ nchunks) {
    int b = blockIdx.x;
    int t = threadIdx.x;
    if (b < 1024) {
        int i = b * 256 + t;
        float4 v = g[i];
        half4 h;
        h[0] = (_Float16)v.x;
        h[1] = (_Float16)v.y;
        h[2] = (_Float16)v.z;
        h[3] = (_Float16)v.w;
        hg[i] = h;
    } else {
        int q = (b - 1024) * 256 + t;
        float4 uu = u4[q];
        int bt = span_base<NT>(uu.x);
        int bd = span_base<ND>(uu.y);
        int bh = span_base<NH>(uu.z);
        int cell = (bt * 13 + bd) * 13 + bh;
        int rank = atomicAdd(&count[cell], 1);
        if (rank < CAP) {
            perm[cell * CAP + rank] = q;
            if ((rank & (CHUNKQ - 1)) == 0) {
                int cid = atomicAdd(nchunks, 1);
                uint2 rec;
                rec.x = (unsigned)(cell * CAP + rank);          // slab start
                rec.y = (unsigned)cell | ((unsigned)(rank / CHUNKQ) << 16);
                chunks[cid] = rec;
            }
        }
    }
}

// ---- main: 512 threads (32 slots x 16 lanes), two passes -> 64 queries/block.
// LDS rows padded to 1040B (65 uint4) to rotate banks per row (conflict fix).
__global__ __launch_bounds__(512) void spline4d_chunk_kernel(
    const float* __restrict__ u, const uint4* __restrict__ hgrid,
    const int* __restrict__ count, const int* __restrict__ perm,
    const uint2* __restrict__ chunks, const int* __restrict__ nchunks,
    float4* __restrict__ out) {
    if ((int)blockIdx.x >= *nchunks) return;

    __shared__ uint4 smem[64 * ROWU4];   // 66.5 KB

    uint2 rec = chunks[blockIdx.x];
    int start = (int)rec.x;                   // slab index of first query
    int cell = (int)(rec.y & 0xffffu);
    int k64 = (int)(rec.y >> 16);
    int len = min(CHUNKQ, count[cell] - k64 * CHUNKQ);

    int bt = cell / 169;
    int r0 = cell - bt * 169;
    int bd = r0 / 13;
    int bh = r0 - bd * 13;

    // stage 64 rows (i,j,k) x 1KB data into padded rows
    for (int idx = (int)threadIdx.x; idx < 64 * ROWU4; idx += 512) {
        int lrow = idx / ROWU4;
        int c = idx - lrow * ROWU4;
        if (c < 64) {
            int i = lrow >> 4, j = (lrow >> 2) & 3, k = lrow & 3;
            int R = ((bt + i) * ND + (bd + j)) * NH + (bh + k);
            smem[idx] = hgrid[R * 64 + c];
        }
    }
    __syncthreads();

    int slot = (int)threadIdx.x >> 4;   // 0..31
    int s = (int)threadIdx.x & 15;
    const half8* slds = reinterpret_cast<const half8*>(smem);

#pragma unroll
    for (int pass = 0; pass < 2; ++pass) {
        int sl = slot + pass * 32;
        if (sl < len) {
            int q = perm[start + sl];
            float4 uu = reinterpret_cast<const float4*>(u)[q];

            int xbt, xbd, xbh, bw;
            float wtv[4], wdv[4], whv[4], wwv[4];
            dim_setup_span<NT>(uu.x, xbt, wtv);
            dim_setup_span<ND>(uu.y, xbd, wdv);
            dim_setup_span<NH>(uu.z, xbh, whv);
            dim_setup_span<NW>(uu.w, bw, wwv);

            int wp = s >> 2;
            float wlane = (wp & 2) ? ((wp & 1) ? wwv[3] : wwv[2])
                                   : ((wp & 1) ? wwv[1] : wwv[0]);

            half2v whW2[4];
#pragma unroll
            for (int k = 0; k < 4; ++k) {
                _Float16 h = (_Float16)(whv[k] * wlane);
                whW2[k][0] = h;
                whW2[k][1] = h;
            }

            float facc[8];
#pragma unroll
            for (int c = 0; c < 8; ++c) facc[c] = 0.0f;
            half2v a01 = {0, 0}, a23 = {0, 0}, a45 = {0, 0}, a67 = {0, 0};

            int lbase = (bw << 2) + s;   // half8 units within a row's data

#pragma unroll
            for (int i = 0; i < 4; ++i) {
#pragma unroll
                for (int j = 0; j < 4; ++j) {
                    _Float16 wtdh = (_Float16)(wtv[i] * wdv[j]);
                    half2v wtd2 = {wtdh, wtdh};
#pragma unroll
                    for (int k = 0; k < 4; ++k) {
                        int lidx = ((i << 4) + (j << 2) + k) * ROWU4 + lbase;
                        H8 P;
                        P.v = slds[lidx];
                        half2v uw = wtd2 * whW2[k];
                        a01 += P.h2[0] * uw;
                        a23 += P.h2[1] * uw;
                        a45 += P.h2[2] * uw;
                        a67 += P.h2[3] * uw;
                    }
                }
                if (i == 1 || i == 3) {
                    facc[0] += (float)a01[0]; facc[1] += (float)a01[1];
                    facc[2] += (float)a23[0]; facc[3] += (float)a23[1];
                    facc[4] += (float)a45[0]; facc[5] += (float)a45[1];
                    facc[6] += (float)a67[0]; facc[7] += (float)a67[1];
                    a01 = (half2v){0, 0}; a23 = (half2v){0, 0};
                    a45 = (half2v){0, 0}; a67 = (half2v){0, 0};
                }
            }

#pragma unroll
            for (int c = 0; c < 8; ++c) {
                facc[c] += __shfl_xor(facc[c], 4);
                facc[c] += __shfl_xor(facc[c], 8);
            }

            if (s < 4) {
                out[q * 8 + s * 2] =
                    make_float4(facc[0], facc[1], facc[2], facc[3]);
                out[q * 8 + s * 2 + 1] =
                    make_float4(facc[4], facc[5], facc[6], facc[7]);
            }
        }
    }
}

// ---- fallback (ws too small): round-6 direct fp16, 52.5us proven ----
__global__ __launch_bounds__(256) void convert_fp16_kernel(
    const float4* __restrict__ g, half4* __restrict__ hg) {
    int i = blockIdx.x * blockDim.x + threadIdx.x;
    float4 v = g[i];
    half4 h;
    h[0] = (_Float16)v.x;
    h[1] = (_Float16)v.y;
    h[2] = (_Float16)v.z;
    h[3] = (_Float16)v.w;
    hg[i] = h;
}

__global__ __launch_bounds__(256) void spline4d_fp16_kernel(
    const float* __restrict__ u, const half8* __restrict__ grid,
    float4* __restrict__ out) {
    int tid = blockIdx.x * blockDim.x + threadIdx.x;
    int q = tid >> 4;
    int s = tid & 15;

    float4 uu = reinterpret_cast<const float4*>(u)[q];

    int bt, bd, bh, bw;
    float wtv[4], wdv[4], whv[4], wwv[4];
    dim_setup_span<NT>(uu.x, bt, wtv);
    dim_setup_span<ND>(uu.y, bd, wdv);
    dim_setup_span<NH>(uu.z, bh, whv);
    dim_setup_span<NW>(uu.w, bw, wwv);

    int wp = s >> 2;
    float wlane = (wp & 2) ? ((wp & 1) ? wwv[3] : wwv[2])
                           : ((wp & 1) ? wwv[1] : wwv[0]);

    half2v whW2[4];
#pragma unroll
    for (int k = 0; k < 4; ++k) {
        _Float16 h = (_Float16)(whv[k] * wlane);
        whW2[k][0] = h;
        whW2[k][1] = h;
    }

    int base = ((((bt * ND + bd) * NH + bh) * NW + bw) << 2) + s;

    float facc[8];
#pragma unroll
    for (int c = 0; c < 8; ++c) facc[c] = 0.0f;
    half2v a01 = {0, 0}, a23 = {0, 0}, a45 = {0, 0}, a67 = {0, 0};

#pragma unroll
    for (int i = 0; i < 4; ++i) {
#pragma unroll
        for (int j = 0; j < 4; ++j) {
            _Float16 wtdh = (_Float16)(wtv[i] * wdv[j]);
            half2v wtd2 = {wtdh, wtdh};
#pragma unroll
            for (int k = 0; k < 4; ++k) {
                int a = base + i * (4 * ND * NH * NW) + j * (4 * NH * NW) +
                        k * (4 * NW);
                H8 P;
                P.v = grid[a];
                half2v uw = wtd2 * whW2[k];
                a01 += P.h2[0] * uw;
                a23 += P.h2[1] * uw;
                a45 += P.h2[2] * uw;
                a67 += P.h2[3] * uw;
            }
        }
        if (i == 1 || i == 3) {
            facc[0] += (float)a01[0]; facc[1] += (float)a01[1];
            facc[2] += (float)a23[0]; facc[3] += (float)a23[1];
            facc[4] += (float)a45[0]; facc[5] += (float)a45[1];
            facc[6] += (float)a67[0]; facc[7] += (float)a67[1];
            a01 = (half2v){0, 0}; a23 = (half2v){0, 0};
            a45 = (half2v){0, 0}; a67 = (half2v){0, 0};
        }
    }

#pragma unroll
    for (int c = 0; c < 8; ++c) {
        facc[c] += __shfl_xor(facc[c], 4);
        facc[c] += __shfl_xor(facc[c], 8);
    }

    if (s < 4) {
        out[q * 8 + s * 2] = make_float4(facc[0], facc[1], facc[2], facc[3]);
        out[q * 8 + s * 2 + 1] = make_float4(facc[4], facc[5], facc[6], facc[7]);
    }
}

extern "C" void kernel_launch(void* const* d_in, const int* in_sizes, int n_in,
                              void* d_out, int out_size, void* d_ws, size_t ws_size,
                              hipStream_t stream) {
    const float* u = (const float*)d_in[0];
    const float* grid_f32 = (const float*)d_in[1];
    float4* out = (float4*)d_out;

    const size_t n_grid_floats = (size_t)NT * ND * NH * NW * NC;  // 1,048,576
    const size_t HG_BYTES = n_grid_floats * 2;                    // 2 MiB

    // workspace layout
    char* ws = (char*)d_ws;
    const size_t OFF_COUNT = HG_BYTES;                   // count: 845*4, pad 4KB
    const size_t OFF_NCH = OFF_COUNT + 4096;             // nchunks: 4B, pad 4KB
    const size_t OFF_CHUNKS = OFF_NCH + 4096;            // 1869*8 -> 16KB
    const size_t OFF_PERM = OFF_CHUNKS + 16384;          // 845*768*4 = 2.596MB
    const size_t NEED = OFF_PERM + (size_t)NCELLS * CAP * 4;  // ~4.64 MB

    if (ws_size >= NEED) {
        half4* hgrid = (half4*)ws;
        int* count = (int*)(ws + OFF_COUNT);
        int* nchunks = (int*)(ws + OFF_NCH);
        uint2* chunks = (uint2*)(ws + OFF_CHUNKS);
        int* perm = (int*)(ws + OFF_PERM);

        hipMemsetAsync(count, 0, 8192, stream);   // zeroes count + nchunks
        prep_kernel<<<1024 + NB / 256, 256, 0, stream>>>(
            (const float4*)grid_f32, hgrid, (const float4*)u, count, perm,
            chunks, nchunks);
        spline4d_chunk_kernel<<<MAXCHUNKS, 512, 0, stream>>>(
            u, (const uint4*)hgrid, count, perm, chunks, nchunks, out);
    } else if (ws_size >= HG_BYTES) {
        half4* hgrid = (half4*)ws;
        int cvt_blocks = (int)(n_grid_floats / 4 / 256);  // 1024
        convert_fp16_kernel<<<cvt_blocks, 256, 0, stream>>>(
            (const float4*)grid_f32, hgrid);
        int nblocks = NB * 16 / 256;
        spline4d_fp16_kernel<<<nblocks, 256, 0, stream>>>(
            u, (const half8*)hgrid, out);
    }
}

// Round 14
// 47.707 us; speedup vs baseline: 4.9184x; 1.4164x over previous
//
#include <hip/hip_runtime.h>

#define NT 8
#define ND 16
#define NH 16
#define NW 16
#define NC 32
#define NB 65536
#define NCELLS (5 * 13 * 13)   // 845 span-base cells (t,d,h)
#define CAP 512                // per-cell slab; expected max ~333 (corner cells)
#define CHUNKQ 32              // queries per chunk == MFMA M
#define MAXCHUNKS (NCELLS + NB / CHUNKQ)   // 845 + 2048 = 2893

typedef _Float16 f16x8 __attribute__((ext_vector_type(8)));
typedef _Float16 half2v __attribute__((ext_vector_type(2)));
typedef _Float16 half4v __attribute__((ext_vector_type(4)));
typedef float f32x16 __attribute__((ext_vector_type(16)));
typedef __attribute__((ext_vector_type(8))) _Float16 half8;

// ---- shared span-base logic (IDENTICAL in binning + main) ----
template <int N>
__device__ __forceinline__ int span_base(float u) {
    float s = u * (float)(N - 1);
    float fi = fminf(fmaxf(floorf(s), 0.0f), (float)(N - 2));
    int i = (int)fi;
    return (i == 0) ? 0 : ((i == N - 2) ? (N - 4) : (i - 1));
}

// Span b..b+3 (in-bounds) + 4 weights with linear-extrapolation padding
// folded in. Validated rounds 3-13 (absmax 7.8e-3).
template <int N>
__device__ __forceinline__ void dim_setup_span(float u, int& b, float w[4]) {
    float s = u * (float)(N - 1);
    float fi = fminf(fmaxf(floorf(s), 0.0f), (float)(N - 2));
    float t = s - fi;
    int i = (int)fi;
    float t2 = t * t, t3 = t2 * t;
    const float c6 = 1.0f / 6.0f;
    float w0 = (1.0f - 3.0f * t + 3.0f * t2 - t3) * c6;
    float w1 = (4.0f - 6.0f * t2 + 3.0f * t3) * c6;
    float w2 = (1.0f + 3.0f * t + 3.0f * t2 - 3.0f * t3) * c6;
    float w3 = t3 * c6;
    if (i == 0) {
        b = 0;
        w[0] = w1 + 2.0f * w0; w[1] = w2 - w0; w[2] = w3; w[3] = 0.0f;
    } else if (i == N - 2) {
        b = N - 4;
        w[0] = 0.0f; w[1] = w0; w[2] = w1 - w3; w[3] = w2 + 2.0f * w3;
    } else {
        b = i - 1;
        w[0] = w0; w[1] = w1; w[2] = w2; w[3] = w3;
    }
}

// ---- prep: blocks 0..255 transpose grid f32[row][w][c] -> f16 gT[row][c][w];
//            blocks 256..511 bin queries into slab + chunk records.
__global__ __launch_bounds__(256) void prep_kernel(
    const float* __restrict__ g, _Float16* __restrict__ gT,
    const float4* __restrict__ u4, int* __restrict__ count,
    int* __restrict__ perm, uint2* __restrict__ chunks,
    int* __restrict__ nchunks) {
    int b = blockIdx.x;
    int t = threadIdx.x;
    if (b < 256) {
        int idx = b * 256 + t;          // 65536 = 2048 rows x 32 channels
        int row = idx >> 5;
        int c = idx & 31;
        const float* src = g + row * 512 + c;   // + w*32 strided reads
        union { _Float16 h[16]; uint4 u[2]; } outv;
#pragma unroll
        for (int w = 0; w < 16; ++w) outv.h[w] = (_Float16)src[w * 32];
        uint4* dst = (uint4*)(gT + (size_t)row * 512 + c * 16);
        dst[0] = outv.u[0];
        dst[1] = outv.u[1];
    } else {
        int q = (b - 256) * 256 + t;
        float4 uu = u4[q];
        int bt = span_base<NT>(uu.x);
        int bd = span_base<ND>(uu.y);
        int bh = span_base<NH>(uu.z);
        int cell = (bt * 13 + bd) * 13 + bh;
        int rank = atomicAdd(&count[cell], 1);
        if (rank < CAP) {
            perm[cell * CAP + rank] = q;
            if ((rank & (CHUNKQ - 1)) == 0) {
                int cid = atomicAdd(nchunks, 1);
                uint2 rec;
                rec.x = (unsigned)(cell * CAP + rank);
                rec.y = (unsigned)cell | ((unsigned)(rank / CHUNKQ) << 16);
                chunks[cid] = rec;
            }
        }
    }
}

// ---- main: one wave (64 threads) per 32-query chunk.
// out[q][c] = sum_r sum_w A[q][rw] * B[rw][c]: M=32 queries, N=32 channels,
// K = 64 rows x 16 w. 64 x mfma_f32_32x32x16_f16; B streamed from the
// transposed grid (coalesced 1KB/row); A built in-reg (w-sparse weights).
// Layouts (cdna4_isa §10, m74/m101): A: m=l&31, k=8*(l>>5)+j;
// B: n=l&31, k=8*(l>>5)+j; C: col=l&31, row=(reg&3)+8*(reg>>2)+4*(l>>5).
__global__ __launch_bounds__(64) void spline4d_mfma_kernel(
    const float* __restrict__ u, const f16x8* __restrict__ gT,
    const int* __restrict__ count, const int* __restrict__ perm,
    const uint2* __restrict__ chunks, const int* __restrict__ nchunks,
    float* __restrict__ out) {
    if ((int)blockIdx.x >= *nchunks) return;

    uint2 rec = chunks[blockIdx.x];
    int start = (int)rec.x;
    int cell = (int)(rec.y & 0xffffu);
    int k32 = (int)(rec.y >> 16);
    int n = min(count[cell], CAP);
    int len = min(CHUNKQ, n - k32 * CHUNKQ);

    int bt = cell / 169;
    int r0 = cell - bt * 169;
    int bd = r0 / 13;
    int bh = r0 - bd * 13;

    int lane = (int)threadIdx.x;
    int slot = lane & 31;        // this lane's query (A row)
    int hi = lane >> 5;          // k-half
    int c = lane & 31;           // channel (B col / C col)

    int q = perm[start + ((slot < len) ? slot : 0)];
    float4 uu = reinterpret_cast<const float4*>(u)[q];

    int xbt, xbd, xbh, bw;
    float wtv[4], wdv[4], whv[4], wwv[4];
    dim_setup_span<NT>(uu.x, xbt, wtv);
    dim_setup_span<ND>(uu.y, xbd, wdv);
    dim_setup_span<NH>(uu.z, xbh, whv);
    dim_setup_span<NW>(uu.w, bw, wwv);
    if (slot >= len) {           // inactive: zero contribution
        wwv[0] = wwv[1] = wwv[2] = wwv[3] = 0.0f;
    }

    // lane's half of the 16-long sparse w-weight vector: w = hi*8 + 0..7
    half2v wf[4];
#pragma unroll
    for (int j2 = 0; j2 < 4; ++j2) {
        int w0 = hi * 8 + 2 * j2;
        int d0 = w0 - bw, d1 = w0 + 1 - bw;
        float v0 = (d0 == 0) ? wwv[0] : (d0 == 1) ? wwv[1]
                 : (d0 == 2) ? wwv[2] : (d0 == 3) ? wwv[3] : 0.0f;
        float v1 = (d1 == 0) ? wwv[0] : (d1 == 1) ? wwv[1]
                 : (d1 == 2) ? wwv[2] : (d1 == 3) ? wwv[3] : 0.0f;
        wf[j2][0] = (_Float16)v0;
        wf[j2][1] = (_Float16)v1;
    }

    // B pointer for this lane: gT row stride = 512 f16 = 64 f16x8;
    // within row: c*16 f16 + hi*8 f16 -> f16x8 index c*2 + hi.
    const f16x8* gp = gT + (c * 2 + hi);

    f32x16 acc;
#pragma unroll
    for (int e = 0; e < 16; ++e) acc[e] = 0.0f;

#pragma unroll
    for (int i = 0; i < 4; ++i) {
        float wti = wtv[i];
#pragma unroll
        for (int j = 0; j < 4; ++j) {
            float wtd = wti * wdv[j];
            int rb = ((bt + i) * ND + (bd + j)) * NH + bh;
#pragma unroll
            for (int k = 0; k < 4; ++k) {
                _Float16 wh = (_Float16)(wtd * whv[k]);
                half2v wb = {wh, wh};
                union { f16x8 v; half2v h[4]; } A;
                A.h[0] = wb * wf[0];
                A.h[1] = wb * wf[1];
                A.h[2] = wb * wf[2];
                A.h[3] = wb * wf[3];
                f16x8 B = gp[(rb + k) * 64];
                acc = __builtin_amdgcn_mfma_f32_32x32x16_f16(A.v, B, acc,
                                                             0, 0, 0);
            }
        }
    }

    // C: lane holds channel c for 16 queries (slots) sreg.
#pragma unroll
    for (int reg = 0; reg < 16; ++reg) {
        int sreg = (reg & 3) + 8 * (reg >> 2) + 4 * hi;
        int qs = __shfl(q, sreg);
        if (sreg < len) out[(size_t)qs * NC + c] = acc[reg];
    }
}

// ---- fallback (ws too small): round-6 direct fp16 (52.5us proven) ----
typedef __attribute__((ext_vector_type(4))) _Float16 half4;

union H8 {
    half8 v;
    half2v h2[4];
};

__global__ __launch_bounds__(256) void convert_fp16_kernel(
    const float4* __restrict__ g, half4* __restrict__ hg) {
    int i = blockIdx.x * blockDim.x + threadIdx.x;
    float4 v = g[i];
    half4 h;
    h[0] = (_Float16)v.x;
    h[1] = (_Float16)v.y;
    h[2] = (_Float16)v.z;
    h[3] = (_Float16)v.w;
    hg[i] = h;
}

__global__ __launch_bounds__(256) void spline4d_fp16_kernel(
    const float* __restrict__ u, const half8* __restrict__ grid,
    float4* __restrict__ out) {
    int tid = blockIdx.x * blockDim.x + threadIdx.x;
    int q = tid >> 4;
    int s = tid & 15;

    float4 uu = reinterpret_cast<const float4*>(u)[q];

    int bt, bd, bh, bw;
    float wtv[4], wdv[4], whv[4], wwv[4];
    dim_setup_span<NT>(uu.x, bt, wtv);
    dim_setup_span<ND>(uu.y, bd, wdv);
    dim_setup_span<NH>(uu.z, bh, whv);
    dim_setup_span<NW>(uu.w, bw, wwv);

    int wp = s >> 2;
    float wlane = (wp & 2) ? ((wp & 1) ? wwv[3] : wwv[2])
                           : ((wp & 1) ? wwv[1] : wwv[0]);

    half2v whW2[4];
#pragma unroll
    for (int k = 0; k < 4; ++k) {
        _Float16 h = (_Float16)(whv[k] * wlane);
        whW2[k][0] = h;
        whW2[k][1] = h;
    }

    int base = ((((bt * ND + bd) * NH + bh) * NW + bw) << 2) + s;

    float facc[8];
#pragma unroll
    for (int c = 0; c < 8; ++c) facc[c] = 0.0f;
    half2v a01 = {0, 0}, a23 = {0, 0}, a45 = {0, 0}, a67 = {0, 0};

#pragma unroll
    for (int i = 0; i < 4; ++i) {
#pragma unroll
        for (int j = 0; j < 4; ++j) {
            _Float16 wtdh = (_Float16)(wtv[i] * wdv[j]);
            half2v wtd2 = {wtdh, wtdh};
#pragma unroll
            for (int k = 0; k < 4; ++k) {
                int a = base + i * (4 * ND * NH * NW) + j * (4 * NH * NW) +
                        k * (4 * NW);
                H8 P;
                P.v = grid[a];
                half2v uw = wtd2 * whW2[k];
                a01 += P.h2[0] * uw;
                a23 += P.h2[1] * uw;
                a45 += P.h2[2] * uw;
                a67 += P.h2[3] * uw;
            }
        }
        if (i == 1 || i == 3) {
            facc[0] += (float)a01[0]; facc[1] += (float)a01[1];
            facc[2] += (float)a23[0]; facc[3] += (float)a23[1];
            facc[4] += (float)a45[0]; facc[5] += (float)a45[1];
            facc[6] += (float)a67[0]; facc[7] += (float)a67[1];
            a01 = (half2v){0, 0}; a23 = (half2v){0, 0};
            a45 = (half2v){0, 0}; a67 = (half2v){0, 0};
        }
    }

#pragma unroll
    for (int c = 0; c < 8; ++c) {
        facc[c] += __shfl_xor(facc[c], 4);
        facc[c] += __shfl_xor(facc[c], 8);
    }

    if (s < 4) {
        out[q * 8 + s * 2] = make_float4(facc[0], facc[1], facc[2], facc[3]);
        out[q * 8 + s * 2 + 1] = make_float4(facc[4], facc[5], facc[6], facc[7]);
    }
}

extern "C" void kernel_launch(void* const* d_in, const int* in_sizes, int n_in,
                              void* d_out, int out_size, void* d_ws, size_t ws_size,
                              hipStream_t stream) {
    const float* u = (const float*)d_in[0];
    const float* grid_f32 = (const float*)d_in[1];

    const size_t n_grid_floats = (size_t)NT * ND * NH * NW * NC;  // 1,048,576
    const size_t GT_BYTES = n_grid_floats * 2;                    // 2 MiB

    char* ws = (char*)d_ws;
    const size_t OFF_COUNT = GT_BYTES;                   // 845*4, pad 4KB
    const size_t OFF_NCH = OFF_COUNT + 4096;             // 4B, pad 4KB
    const size_t OFF_CHUNKS = OFF_NCH + 4096;            // 2893*8 -> 24KB
    const size_t OFF_PERM = OFF_CHUNKS + 24576;          // 845*512*4 = 1.73MB
    const size_t NEED = OFF_PERM + (size_t)NCELLS * CAP * 4;   // ~3.8 MB

    if (ws_size >= NEED) {
        _Float16* gT = (_Float16*)ws;
        int* count = (int*)(ws + OFF_COUNT);
        int* nchunks = (int*)(ws + OFF_NCH);
        uint2* chunks = (uint2*)(ws + OFF_CHUNKS);
        int* perm = (int*)(ws + OFF_PERM);

        hipMemsetAsync(count, 0, 8192, stream);   // zeroes count + nchunks
        prep_kernel<<<512, 256, 0, stream>>>(
            grid_f32, gT, (const float4*)u, count, perm, chunks, nchunks);
        spline4d_mfma_kernel<<<MAXCHUNKS, 64, 0, stream>>>(
            u, (const f16x8*)gT, count, perm, chunks, nchunks, (float*)d_out);
    } else if (ws_size >= GT_BYTES) {
        half4* hgrid = (half4*)ws;
        int cvt_blocks = (int)(n_grid_floats / 4 / 256);  // 1024
        convert_fp16_kernel<<<cvt_blocks, 256, 0, stream>>>(
            (const float4*)grid_f32, hgrid);
        int nblocks = NB * 16 / 256;
        spline4d_fp16_kernel<<<nblocks, 256, 0, stream>>>(
            u, (const half8*)hgrid, (float4*)d_out);
    }
}